// Round 2
// baseline (2412.575 us; speedup 1.0000x reference)
//
#include <hip/hip_runtime.h>
#include <math.h>

#define NNODES 100000
#define NEDGES 3200000

// ---------------- CSR build ----------------
__global__ void init_cnt(int* cnt, int n) {
    int i = blockIdx.x * blockDim.x + threadIdx.x;
    if (i < n) cnt[i] = 1;  // self loop contributes 1 to degree
}

__global__ void count_deg(const int* __restrict__ dst, int e, int* cnt) {
    int i = blockIdx.x * blockDim.x + threadIdx.x;
    if (i < e) atomicAdd(&cnt[dst[i]], 1);
}

__global__ void compute_dinv(const int* __restrict__ cnt, float* __restrict__ dinv, int n) {
    int i = blockIdx.x * blockDim.x + threadIdx.x;
    if (i < n) dinv[i] = rsqrtf((float)cnt[i]);  // cnt >= 1 always (self loop)
}

// single-block exclusive scan of cnt -> rowptr (n=100000, 1024 threads)
__global__ void scan_rowptr(const int* __restrict__ cnt, int* __restrict__ rowptr, int n) {
    __shared__ int sums[1024];
    int t = threadIdx.x;
    int chunk = (n + 1023) / 1024;
    int lo = t * chunk;
    int hi = lo + chunk; if (hi > n) hi = n;
    int s = 0;
    for (int i = lo; i < hi; ++i) s += cnt[i];
    sums[t] = s;
    __syncthreads();
    // Hillis-Steele inclusive scan
    for (int off = 1; off < 1024; off <<= 1) {
        int v = (t >= off) ? sums[t - off] : 0;
        __syncthreads();
        sums[t] += v;
        __syncthreads();
    }
    int run = (t == 0) ? 0 : sums[t - 1];
    for (int i = lo; i < hi; ++i) { rowptr[i] = run; run += cnt[i]; }
    if (t == 1023) rowptr[n] = sums[1023];
}

// reserve slot rowptr[i] for the self loop, pos starts after it
__global__ void init_pos(const int* __restrict__ rowptr, int* __restrict__ pos,
                         int* __restrict__ esrc, int n) {
    int i = blockIdx.x * blockDim.x + threadIdx.x;
    if (i < n) { int r = rowptr[i]; esrc[r] = i; pos[i] = r + 1; }
}

__global__ void fill_edges(const int* __restrict__ src, const int* __restrict__ dst, int e,
                           int* pos, int* __restrict__ esrc) {
    int i = blockIdx.x * blockDim.x + threadIdx.x;
    if (i < e) { int p = atomicAdd(&pos[dst[i]], 1); esrc[p] = src[i]; }
}

// ---------------- f32 tiled GEMM, epilogue scales row by dinv[m] ----------------
// C[m][n] = (sum_k A[m][k]*B[k][n]) * dinv[m]
template <int BM, int BN, int BK>
__launch_bounds__(256)
__global__ void gemm_scale(const float* __restrict__ A, const float* __restrict__ B,
                           const float* __restrict__ dinv, float* __restrict__ C,
                           int M, int N, int K) {
    __shared__ float As[BK][BM + 1];   // +1 pad: avoid bank conflicts on transpose write
    __shared__ float Bs[BK][BN];
    const int tid = threadIdx.x;               // 256 threads
    const int tx = tid & 15, ty = tid >> 4;    // 16x16
    const int m0 = blockIdx.y * BM, n0 = blockIdx.x * BN;

    float acc[4][4] = {};
    const bool nvec = ((N & 3) == 0);

    for (int k0 = 0; k0 < K; k0 += BK) {
        // A tile: BM x BK (transposed into LDS)
        for (int idx = tid; idx < BM * (BK / 4); idx += 256) {
            int row = idx / (BK / 4);
            int kq  = idx % (BK / 4);
            int gm = m0 + row;
            float4 v = make_float4(0.f, 0.f, 0.f, 0.f);
            if (gm < M) v = *(const float4*)&A[(size_t)gm * K + k0 + kq * 4];
            As[kq * 4 + 0][row] = v.x;
            As[kq * 4 + 1][row] = v.y;
            As[kq * 4 + 2][row] = v.z;
            As[kq * 4 + 3][row] = v.w;
        }
        // B tile: BK x BN
        for (int idx = tid; idx < BK * (BN / 4); idx += 256) {
            int krow = idx / (BN / 4);
            int nq   = idx % (BN / 4);
            int gn = n0 + nq * 4;
            const float* Brow = B + (size_t)(k0 + krow) * N;
            float4 v;
            if (nvec && gn + 3 < N) {
                v = *(const float4*)(Brow + gn);
            } else {
                v.x = (gn + 0 < N) ? Brow[gn + 0] : 0.f;
                v.y = (gn + 1 < N) ? Brow[gn + 1] : 0.f;
                v.z = (gn + 2 < N) ? Brow[gn + 2] : 0.f;
                v.w = (gn + 3 < N) ? Brow[gn + 3] : 0.f;
            }
            Bs[krow][nq * 4 + 0] = v.x;
            Bs[krow][nq * 4 + 1] = v.y;
            Bs[krow][nq * 4 + 2] = v.z;
            Bs[krow][nq * 4 + 3] = v.w;
        }
        __syncthreads();
        #pragma unroll
        for (int k = 0; k < BK; ++k) {
            float a[4], b[4];
            #pragma unroll
            for (int i = 0; i < 4; ++i) a[i] = As[k][ty * 4 + i];
            #pragma unroll
            for (int j = 0; j < 4; ++j) b[j] = Bs[k][tx * 4 + j];
            #pragma unroll
            for (int i = 0; i < 4; ++i)
                #pragma unroll
                for (int j = 0; j < 4; ++j) acc[i][j] += a[i] * b[j];
        }
        __syncthreads();
    }

    #pragma unroll
    for (int i = 0; i < 4; ++i) {
        int gm = m0 + ty * 4 + i;
        if (gm >= M) continue;
        float d = dinv[gm];
        #pragma unroll
        for (int j = 0; j < 4; ++j) {
            int gn = n0 + tx * 4 + j;
            if (gn < N) C[(size_t)gm * N + gn] = acc[i][j] * d;
        }
    }
}

// ---------------- aggregation: out[i] = relu?(dinv[i]*sum_src h[src] + b) ----------------
template <int F, int TPN, int RELU>
__global__ void aggregate(const float* __restrict__ h, const int* __restrict__ rowptr,
                          const int* __restrict__ esrc, const float* __restrict__ dinv,
                          const float* __restrict__ bias, float* __restrict__ out, int n) {
    const int nodesPerBlock = 256 / TPN;
    const int local = threadIdx.x / TPN;
    const int j = threadIdx.x % TPN;
    const int i = blockIdx.x * nodesPerBlock + local;
    if (i >= n) return;
    const int lo = rowptr[i], hi = rowptr[i + 1];
    if (j < F) {
        float acc = 0.f;
        for (int e = lo; e < hi; ++e) {
            int s = esrc[e];
            acc += h[(size_t)s * F + j];
        }
        float v = acc * dinv[i] + bias[j];
        if (RELU) v = fmaxf(v, 0.f);
        out[(size_t)i * F + j] = v;
    }
}

// layer 3: aggregate (F=10) + bias + log_softmax fused, 16 lanes per node
__global__ void aggregate_logsoftmax(const float* __restrict__ h, const int* __restrict__ rowptr,
                                     const int* __restrict__ esrc, const float* __restrict__ dinv,
                                     const float* __restrict__ bias, float* __restrict__ out, int n) {
    const int F = 10, TPN = 16;
    const int local = threadIdx.x / TPN;
    const int j = threadIdx.x % TPN;
    const int i = blockIdx.x * (256 / TPN) + local;
    if (i >= n) return;
    const int lo = rowptr[i], hi = rowptr[i + 1];
    float acc = 0.f;
    if (j < F) {
        for (int e = lo; e < hi; ++e) {
            int s = esrc[e];
            acc += h[(size_t)s * F + j];
        }
    }
    float v = (j < F) ? (acc * dinv[i] + bias[j]) : -INFINITY;
    float m = v;
    #pragma unroll
    for (int off = 1; off < 16; off <<= 1) m = fmaxf(m, __shfl_xor(m, off, 16));
    float e = (j < F) ? expf(v - m) : 0.f;
    float s = e;
    #pragma unroll
    for (int off = 1; off < 16; off <<= 1) s += __shfl_xor(s, off, 16);
    if (j < F) out[(size_t)i * F + j] = v - m - logf(s);
}

extern "C" void kernel_launch(void* const* d_in, const int* in_sizes, int n_in,
                              void* d_out, int out_size, void* d_ws, size_t ws_size,
                              hipStream_t stream) {
    const int N = NNODES, E = NEDGES;
    const float* x  = (const float*)d_in[0];
    const int*   ei = (const int*)d_in[1];     // [2, E] int32
    const float* W1 = (const float*)d_in[2];
    const float* b1 = (const float*)d_in[3];
    const float* W2 = (const float*)d_in[4];
    const float* b2 = (const float*)d_in[5];
    const float* W3 = (const float*)d_in[6];
    const float* b3 = (const float*)d_in[7];
    float* out = (float*)d_out;
    const int* src = ei;
    const int* dst = ei + E;

    // workspace carve-up
    char* ws = (char*)d_ws;
    size_t off = 0;
    auto alloc = [&](size_t bytes) -> void* {
        void* p = ws + off;
        off = (off + bytes + 255) & ~(size_t)255;
        return p;
    };
    float* dinv   = (float*)alloc((size_t)N * 4);
    int*   cnt    = (int*)alloc((size_t)N * 4);
    int*   rowptr = (int*)alloc((size_t)(N + 1) * 4);
    int*   pos    = (int*)alloc((size_t)N * 4);
    int*   esrc   = (int*)alloc((size_t)(E + N) * 4);
    float* bufA   = (float*)alloc((size_t)N * 256 * 4);
    float* bufB   = (float*)alloc((size_t)N * 256 * 4);

    const int T = 256;
    // CSR build
    init_cnt<<<(N + T - 1) / T, T, 0, stream>>>(cnt, N);
    count_deg<<<(E + T - 1) / T, T, 0, stream>>>(dst, E, cnt);
    compute_dinv<<<(N + T - 1) / T, T, 0, stream>>>(cnt, dinv, N);
    scan_rowptr<<<1, 1024, 0, stream>>>(cnt, rowptr, N);
    init_pos<<<(N + T - 1) / T, T, 0, stream>>>(rowptr, pos, esrc, N);
    fill_edges<<<(E + T - 1) / T, T, 0, stream>>>(src, dst, E, pos, esrc);

    const int MB = (N + 63) / 64;  // 1563

    // Layer 1: h1 = (x @ W1) * dinv -> bufA ; agg(+b1, relu) -> bufB
    gemm_scale<64, 64, 32><<<dim3(256 / 64, MB), 256, 0, stream>>>(x, W1, dinv, bufA, N, 256, 512);
    aggregate<256, 256, 1><<<N, 256, 0, stream>>>(bufA, rowptr, esrc, dinv, b1, bufB, N);

    // Layer 2: h2 = (bufB @ W2) * dinv -> bufA ; agg(+b2, relu) -> bufB
    gemm_scale<64, 64, 32><<<dim3(1, MB), 256, 0, stream>>>(bufB, W2, dinv, bufA, N, 64, 256);
    aggregate<64, 64, 1><<<(N + 3) / 4, 256, 0, stream>>>(bufA, rowptr, esrc, dinv, b2, bufB, N);

    // Layer 3: h3 = (bufB @ W3) * dinv -> bufA ; agg(+b3) + log_softmax -> out
    gemm_scale<64, 64, 32><<<dim3(1, MB), 256, 0, stream>>>(bufB, W3, dinv, bufA, N, 10, 64);
    aggregate_logsoftmax<<<(N + 15) / 16, 256, 0, stream>>>(bufA, rowptr, esrc, dinv, b3, out, N);
}

// Round 3
// 1022.740 us; speedup vs baseline: 2.3589x; 2.3589x over previous
//
#include <hip/hip_runtime.h>
#include <math.h>

#define NNODES 100000
#define NEDGES 3200000

typedef __attribute__((ext_vector_type(4))) float f32x4;
typedef __attribute__((ext_vector_type(8))) short bf16x8;

__device__ __forceinline__ float bf2f(ushort u) {
    union { unsigned u; float f; } v; v.u = ((unsigned)u) << 16; return v.f;
}
__device__ __forceinline__ ushort f2bf(float f) {
    union { float f; unsigned u; } v; v.f = f;
    unsigned r = v.u + 0x7FFFu + ((v.u >> 16) & 1u);
    return (ushort)(r >> 16);
}

// ---------------- CSR build ----------------
__global__ void init_cnt(int* cnt, int n) {
    int i = blockIdx.x * blockDim.x + threadIdx.x;
    if (i < n) cnt[i] = 1;  // self loop
}

__global__ void count_deg(const int* __restrict__ dst, int e, int* cnt) {
    int i = blockIdx.x * blockDim.x + threadIdx.x;
    if (i < e) atomicAdd(&cnt[dst[i]], 1);
}

__global__ void compute_dinv(const int* __restrict__ cnt, float* __restrict__ dinv, int n) {
    int i = blockIdx.x * blockDim.x + threadIdx.x;
    if (i < n) dinv[i] = rsqrtf((float)cnt[i]);
}

__global__ void scan_rowptr(const int* __restrict__ cnt, int* __restrict__ rowptr, int n) {
    __shared__ int sums[1024];
    int t = threadIdx.x;
    int chunk = (n + 1023) / 1024;
    int lo = t * chunk;
    int hi = lo + chunk; if (hi > n) hi = n;
    int s = 0;
    for (int i = lo; i < hi; ++i) s += cnt[i];
    sums[t] = s;
    __syncthreads();
    for (int off = 1; off < 1024; off <<= 1) {
        int v = (t >= off) ? sums[t - off] : 0;
        __syncthreads();
        sums[t] += v;
        __syncthreads();
    }
    int run = (t == 0) ? 0 : sums[t - 1];
    for (int i = lo; i < hi; ++i) { rowptr[i] = run; run += cnt[i]; }
    if (t == 1023) rowptr[n] = sums[1023];
}

__global__ void init_pos(const int* __restrict__ rowptr, int* __restrict__ pos,
                         int* __restrict__ esrc, int n) {
    int i = blockIdx.x * blockDim.x + threadIdx.x;
    if (i < n) { int r = rowptr[i]; esrc[r] = i; pos[i] = r + 1; }
}

__global__ void fill_edges(const int* __restrict__ src, const int* __restrict__ dst, int e,
                           int* pos, int* __restrict__ esrc) {
    int i = blockIdx.x * blockDim.x + threadIdx.x;
    if (i < e) { int p = atomicAdd(&pos[dst[i]], 1); esrc[p] = src[i]; }
}

// ---------------- conversions ----------------
__global__ void conv_bf16(const float* __restrict__ x, ushort* __restrict__ xb, long n4) {
    long i = (long)blockIdx.x * blockDim.x + threadIdx.x;
    long stride = (long)gridDim.x * blockDim.x;
    for (; i < n4; i += stride) {
        float4 v = ((const float4*)x)[i];
        ushort4 o;
        o.x = f2bf(v.x); o.y = f2bf(v.y); o.z = f2bf(v.z); o.w = f2bf(v.w);
        ((ushort4*)xb)[i] = o;
    }
}

// Wt[n][k] = bf16(W[k][n]); rows n>=N zero-padded
__global__ void conv_wt(const float* __restrict__ W, ushort* __restrict__ Wt,
                        int K, int N, int Npad) {
    int idx = blockIdx.x * blockDim.x + threadIdx.x;
    if (idx >= Npad * K) return;
    int n = idx / K, k = idx % K;
    Wt[idx] = (n < N) ? f2bf(W[(size_t)k * N + n]) : (ushort)0;
}

// ---------------- bf16 MFMA GEMM: C[m][n] = (sum_k A[m][k]*Bt[n][k]) * dinv[m] ----------------
template <int BM, int BN, int BK, int WM, int WN, bool OUTF32>
__launch_bounds__(WM* WN * 64)
__global__ void gemm_bf16(const ushort* __restrict__ A, const ushort* __restrict__ Bt,
                          const float* __restrict__ dinv, void* __restrict__ Cout,
                          int M, int N, int K) {
    constexpr int NT = WM * WN * 64;
    __shared__ __align__(16) ushort As[BM][BK];
    __shared__ __align__(16) ushort Bs[BN][BK];
    const int tid = threadIdx.x;
    const int wid = tid >> 6, lane = tid & 63;
    const int wr = wid / WN, wc = wid % WN;
    constexpr int TM = BM / WM, TN = BN / WN;
    constexpr int FM = TM / 16, FN = TN / 16;
    const int m0 = blockIdx.y * BM, n0 = blockIdx.x * BN;
    const int ln = lane & 15, ks = (lane >> 4) * 8;

    f32x4 acc[FM][FN] = {};

    constexpr int ACH = BM * BK / 8;  // 16B chunks
    constexpr int BCH = BN * BK / 8;
    constexpr int CPR = BK / 8;       // chunks per row

    for (int k0 = 0; k0 < K; k0 += BK) {
        // stage A tile (linear LDS, global_load_lds width 16)
        #pragma unroll
        for (int it = 0; it < (ACH + NT - 1) / NT; ++it) {
            int c = it * NT + tid;
            if ((ACH % NT == 0) || (c < ACH)) {
                int row = c / CPR, ch = c % CPR;
                int gm = m0 + row; if (gm >= M) gm = M - 1;
                const ushort* gp = &A[(size_t)gm * K + k0 + ch * 8];
                __builtin_amdgcn_global_load_lds(
                    (const __attribute__((address_space(1))) void*)gp,
                    (__attribute__((address_space(3))) void*)((char*)&As[0][0] + c * 16),
                    16, 0, 0);
            }
        }
        // stage B tile
        #pragma unroll
        for (int it = 0; it < (BCH + NT - 1) / NT; ++it) {
            int c = it * NT + tid;
            if ((BCH % NT == 0) || (c < BCH)) {
                int row = c / CPR, ch = c % CPR;
                const ushort* gp = &Bt[(size_t)(n0 + row) * K + k0 + ch * 8];
                __builtin_amdgcn_global_load_lds(
                    (const __attribute__((address_space(1))) void*)gp,
                    (__attribute__((address_space(3))) void*)((char*)&Bs[0][0] + c * 16),
                    16, 0, 0);
            }
        }
        __syncthreads();

        bf16x8 af[FM], bf[FN];
        #pragma unroll
        for (int mi = 0; mi < FM; ++mi)
            af[mi] = *(const bf16x8*)&As[wr * TM + mi * 16 + ln][ks];
        #pragma unroll
        for (int nj = 0; nj < FN; ++nj)
            bf[nj] = *(const bf16x8*)&Bs[wc * TN + nj * 16 + ln][ks];
        #pragma unroll
        for (int mi = 0; mi < FM; ++mi)
            #pragma unroll
            for (int nj = 0; nj < FN; ++nj)
                acc[mi][nj] = __builtin_amdgcn_mfma_f32_16x16x32_bf16(af[mi], bf[nj], acc[mi][nj], 0, 0, 0);
        __syncthreads();
    }

    const int rbase = (lane >> 4) * 4;  // C/D: col=lane&15, row=(lane>>4)*4+reg
    #pragma unroll
    for (int mi = 0; mi < FM; ++mi) {
        #pragma unroll
        for (int r = 0; r < 4; ++r) {
            int gm = m0 + wr * TM + mi * 16 + rbase + r;
            if (gm >= M) continue;
            float d = dinv[gm];
            #pragma unroll
            for (int nj = 0; nj < FN; ++nj) {
                int gn = n0 + wc * TN + nj * 16 + ln;
                float v = acc[mi][nj][r] * d;
                if (OUTF32) ((float*)Cout)[(size_t)gm * N + gn] = v;
                else        ((ushort*)Cout)[(size_t)gm * N + gn] = f2bf(v);
            }
        }
    }
}

// ---------------- aggregation (bf16 in/out), wave-per-node, 4-edge ILP ----------------
// out[i][:] = relu(dinv[i] * sum_{s in adj(i)} h[s][:] + bias)
__global__ void agg1_kernel(const ushort* __restrict__ h, const int* __restrict__ rowptr,
                            const int* __restrict__ esrc, const float* __restrict__ dinv,
                            const float* __restrict__ bias, ushort* __restrict__ out, int n) {
    const int wid = threadIdx.x >> 6, lane = threadIdx.x & 63;
    const int i = blockIdx.x * 4 + wid;
    if (i >= n) return;
    const int lo = rowptr[i], hi = rowptr[i + 1];
    const int f0 = lane * 4;
    float ax = 0.f, ay = 0.f, az = 0.f, aw = 0.f;
    int e = lo;
    for (; e + 3 < hi; e += 4) {
        int s0 = esrc[e], s1 = esrc[e + 1], s2 = esrc[e + 2], s3 = esrc[e + 3];
        ushort4 v0 = *(const ushort4*)&h[(size_t)s0 * 256 + f0];
        ushort4 v1 = *(const ushort4*)&h[(size_t)s1 * 256 + f0];
        ushort4 v2 = *(const ushort4*)&h[(size_t)s2 * 256 + f0];
        ushort4 v3 = *(const ushort4*)&h[(size_t)s3 * 256 + f0];
        ax += bf2f(v0.x) + bf2f(v1.x) + bf2f(v2.x) + bf2f(v3.x);
        ay += bf2f(v0.y) + bf2f(v1.y) + bf2f(v2.y) + bf2f(v3.y);
        az += bf2f(v0.z) + bf2f(v1.z) + bf2f(v2.z) + bf2f(v3.z);
        aw += bf2f(v0.w) + bf2f(v1.w) + bf2f(v2.w) + bf2f(v3.w);
    }
    for (; e < hi; ++e) {
        int s = esrc[e];
        ushort4 v = *(const ushort4*)&h[(size_t)s * 256 + f0];
        ax += bf2f(v.x); ay += bf2f(v.y); az += bf2f(v.z); aw += bf2f(v.w);
    }
    float d = dinv[i];
    float4 b = *(const float4*)&bias[f0];
    ushort4 o;
    o.x = f2bf(fmaxf(ax * d + b.x, 0.f));
    o.y = f2bf(fmaxf(ay * d + b.y, 0.f));
    o.z = f2bf(fmaxf(az * d + b.z, 0.f));
    o.w = f2bf(fmaxf(aw * d + b.w, 0.f));
    *(ushort4*)&out[(size_t)i * 256 + f0] = o;
}

// F=64: 16 lanes per node, 4 feats/lane
__global__ void agg2_kernel(const ushort* __restrict__ h, const int* __restrict__ rowptr,
                            const int* __restrict__ esrc, const float* __restrict__ dinv,
                            const float* __restrict__ bias, ushort* __restrict__ out, int n) {
    const int g = threadIdx.x >> 4, j = threadIdx.x & 15;
    const int i = blockIdx.x * 16 + g;
    if (i >= n) return;
    const int lo = rowptr[i], hi = rowptr[i + 1];
    const int f0 = j * 4;
    float ax = 0.f, ay = 0.f, az = 0.f, aw = 0.f;
    int e = lo;
    for (; e + 3 < hi; e += 4) {
        int s0 = esrc[e], s1 = esrc[e + 1], s2 = esrc[e + 2], s3 = esrc[e + 3];
        ushort4 v0 = *(const ushort4*)&h[(size_t)s0 * 64 + f0];
        ushort4 v1 = *(const ushort4*)&h[(size_t)s1 * 64 + f0];
        ushort4 v2 = *(const ushort4*)&h[(size_t)s2 * 64 + f0];
        ushort4 v3 = *(const ushort4*)&h[(size_t)s3 * 64 + f0];
        ax += bf2f(v0.x) + bf2f(v1.x) + bf2f(v2.x) + bf2f(v3.x);
        ay += bf2f(v0.y) + bf2f(v1.y) + bf2f(v2.y) + bf2f(v3.y);
        az += bf2f(v0.z) + bf2f(v1.z) + bf2f(v2.z) + bf2f(v3.z);
        aw += bf2f(v0.w) + bf2f(v1.w) + bf2f(v2.w) + bf2f(v3.w);
    }
    for (; e < hi; ++e) {
        int s = esrc[e];
        ushort4 v = *(const ushort4*)&h[(size_t)s * 64 + f0];
        ax += bf2f(v.x); ay += bf2f(v.y); az += bf2f(v.z); aw += bf2f(v.w);
    }
    float d = dinv[i];
    float4 b = *(const float4*)&bias[f0];
    ushort4 o;
    o.x = f2bf(fmaxf(ax * d + b.x, 0.f));
    o.y = f2bf(fmaxf(ay * d + b.y, 0.f));
    o.z = f2bf(fmaxf(az * d + b.z, 0.f));
    o.w = f2bf(fmaxf(aw * d + b.w, 0.f));
    *(ushort4*)&out[(size_t)i * 64 + f0] = o;
}

// layer 3: h3 f32 [n][16] (cols 10..15 are zeros) -> out f32 [n][10], fused log_softmax
__global__ void agg3_logsoftmax(const float* __restrict__ h3, const int* __restrict__ rowptr,
                                const int* __restrict__ esrc, const float* __restrict__ dinv,
                                const float* __restrict__ bias, float* __restrict__ out, int n) {
    const int g = threadIdx.x >> 4, j = threadIdx.x & 15;
    const int i = blockIdx.x * 16 + g;
    if (i >= n) return;
    const int lo = rowptr[i], hi = rowptr[i + 1];
    float acc = 0.f;
    int e = lo;
    for (; e + 3 < hi; e += 4) {
        int s0 = esrc[e], s1 = esrc[e + 1], s2 = esrc[e + 2], s3 = esrc[e + 3];
        float v0 = h3[(size_t)s0 * 16 + j];
        float v1 = h3[(size_t)s1 * 16 + j];
        float v2 = h3[(size_t)s2 * 16 + j];
        float v3 = h3[(size_t)s3 * 16 + j];
        acc += v0 + v1 + v2 + v3;
    }
    for (; e < hi; ++e) acc += h3[(size_t)esrc[e] * 16 + j];
    float v = (j < 10) ? (acc * dinv[i] + bias[j]) : -INFINITY;
    float m = v;
    #pragma unroll
    for (int off = 1; off < 16; off <<= 1) m = fmaxf(m, __shfl_xor(m, off, 16));
    float ex = (j < 10) ? expf(v - m) : 0.f;
    float s = ex;
    #pragma unroll
    for (int off = 1; off < 16; off <<= 1) s += __shfl_xor(s, off, 16);
    if (j < 10) out[(size_t)i * 10 + j] = v - m - logf(s);
}

extern "C" void kernel_launch(void* const* d_in, const int* in_sizes, int n_in,
                              void* d_out, int out_size, void* d_ws, size_t ws_size,
                              hipStream_t stream) {
    const int N = NNODES, E = NEDGES;
    const float* x  = (const float*)d_in[0];
    const int*   ei = (const int*)d_in[1];
    const float* W1 = (const float*)d_in[2];
    const float* b1 = (const float*)d_in[3];
    const float* W2 = (const float*)d_in[4];
    const float* b2 = (const float*)d_in[5];
    const float* W3 = (const float*)d_in[6];
    const float* b3 = (const float*)d_in[7];
    float* out = (float*)d_out;
    const int* src = ei;
    const int* dst = ei + E;

    char* ws = (char*)d_ws;
    size_t off = 0;
    auto alloc = [&](size_t bytes) -> void* {
        void* p = ws + off;
        off = (off + bytes + 255) & ~(size_t)255;
        return p;
    };
    float* dinv   = (float*)alloc((size_t)N * 4);
    int*   cnt    = (int*)alloc((size_t)N * 4);
    int*   rowptr = (int*)alloc((size_t)(N + 1) * 4);
    int*   pos    = (int*)alloc((size_t)N * 4);
    int*   esrc   = (int*)alloc((size_t)(E + N) * 4);
    ushort* xb    = (ushort*)alloc((size_t)N * 512 * 2);   // also reused as h3f after gemm1
    ushort* W1t   = (ushort*)alloc((size_t)256 * 512 * 2);
    ushort* W2t   = (ushort*)alloc((size_t)64 * 256 * 2);
    ushort* W3t   = (ushort*)alloc((size_t)16 * 64 * 2);
    ushort* buf1  = (ushort*)alloc((size_t)N * 256 * 2);
    ushort* buf2  = (ushort*)alloc((size_t)N * 256 * 2);
    float* h3f    = (float*)xb;  // [N][16] f32, xb dead after gemm1

    const int T = 256;
    init_cnt<<<(N + T - 1) / T, T, 0, stream>>>(cnt, N);
    count_deg<<<(E + T - 1) / T, T, 0, stream>>>(dst, E, cnt);
    compute_dinv<<<(N + T - 1) / T, T, 0, stream>>>(cnt, dinv, N);
    scan_rowptr<<<1, 1024, 0, stream>>>(cnt, rowptr, N);
    init_pos<<<(N + T - 1) / T, T, 0, stream>>>(rowptr, pos, esrc, N);
    fill_edges<<<(E + T - 1) / T, T, 0, stream>>>(src, dst, E, pos, esrc);

    conv_bf16<<<2048, T, 0, stream>>>(x, xb, (long)N * 512 / 4);
    conv_wt<<<(256 * 512 + T - 1) / T, T, 0, stream>>>(W1, W1t, 512, 256, 256);
    conv_wt<<<(64 * 256 + T - 1) / T, T, 0, stream>>>(W2, W2t, 256, 64, 64);
    conv_wt<<<(16 * 64 + T - 1) / T, T, 0, stream>>>(W3, W3t, 64, 10, 16);

    const int MB = (N + 127) / 128;  // 782

    // Layer 1
    gemm_bf16<128, 128, 32, 2, 2, false><<<dim3(2, MB), 256, 0, stream>>>(xb, W1t, dinv, buf1, N, 256, 512);
    agg1_kernel<<<(N + 3) / 4, 256, 0, stream>>>(buf1, rowptr, esrc, dinv, b1, buf2, N);

    // Layer 2
    gemm_bf16<128, 64, 32, 2, 2, false><<<dim3(1, MB), 256, 0, stream>>>(buf2, W2t, dinv, buf1, N, 64, 256);
    agg2_kernel<<<(N + 15) / 16, 256, 0, stream>>>(buf1, rowptr, esrc, dinv, b2, buf2, N);

    // Layer 3 (N padded to 16, f32 out)
    gemm_bf16<128, 16, 32, 4, 1, true><<<dim3(1, MB), 256, 0, stream>>>(buf2, W3t, dinv, h3f, N, 16, 64);
    agg3_logsoftmax<<<(N + 15) / 16, 256, 0, stream>>>(h3f, rowptr, esrc, dinv, b3, out, N);
}